// Round 6
// baseline (146.278 us; speedup 1.0000x reference)
//
#include <hip/hip_runtime.h>

#define BATCH 64
#define GRIDW 38
#define HW 1444            // 38*38
#define NBOX 16
#define NANC 5
#define NCLS 20
#define SLOTS 7220         // HW * NANC
#define CIN 125            // (21+4)*5
#define EPSC 0.0009765625f // 2^-10
#define BPB 29             // blocks per batch = ceil(7220/256)
#define NBLK (BATCH * BPB) // 1856
#define PSTRIDE 8          // cols: 5 loss terms, c_pos, c_ign, pad
#define MAGIC 0x5EEDFACEu

struct BoxRec {
  int   cell;   // row*38+col
  int   ids;    // best anchor
  int   lab;    // glabel-1 in [0,20)
  float tx, ty, tw, th;
  float wleft;  // gboxes_ltrb[...,0] — the reference's "w_pos" (index 26 bug)
};

__constant__ float ANCW[5] = {0.05f, 0.12f, 0.25f, 0.45f, 0.75f};
__constant__ float ANCH[5] = {0.07f, 0.15f, 0.30f, 0.55f, 0.80f};

// Single launch, 1856 blocks (1 slot/thread -> ~29 waves/CU hides load latency;
// R4's 64-block grid was 1 wave/CU and 52us of exposed latency).
// Completion: each block release-stores a MAGIC flag after writing its 8
// partials; block 0 (after its own slot work) parallel-spins on all 1856
// flags (256 threads x ~7 flags), fences, then reduces partials with
// pipelined independent loads. Poison-safe: 0xAA != MAGIC, no memset needed.
__global__ void __launch_bounds__(256) fused_kernel(
    const float* __restrict__ pyolos,
    const float* __restrict__ gboxes,
    const int* __restrict__ glabels,
    float* __restrict__ partials,        // [NBLK][PSTRIDE]
    unsigned int* __restrict__ flags,    // [NBLK]
    float* __restrict__ out) {
  int b     = blockIdx.x / BPB;
  int chunk = blockIdx.x - b * BPB;

  __shared__ BoxRec sbox[NBOX];
  if (threadIdx.x < NBOX) {
    int n = threadIdx.x;
    const float* gb = gboxes + ((size_t)b * NBOX + n) * 4;
    float l  = gb[0], t = gb[1], r = gb[2], bt = gb[3];
    float cx = (l + r) * 0.5f, cy = (t + bt) * 0.5f;
    float w  = r - l,          h  = bt - t;
    int best = 0; float bestv = -1.0f;
    #pragma unroll
    for (int a = 0; a < NANC; ++a) {
      float inter = fminf(w, ANCW[a]) * fminf(h, ANCH[a]);
      float uni   = w * h + ANCW[a] * ANCH[a] - inter;
      float iou   = inter / uni;
      if (iou > bestv) { bestv = iou; best = a; }  // strict >: first-max (jnp.argmax)
    }
    int col = (int)floorf(cx * (float)GRIDW);
    int row = (int)floorf(cy * (float)GRIDW);
    col = min(max(col, 0), GRIDW - 1);
    row = min(max(row, 0), GRIDW - 1);
    BoxRec rec;
    rec.cell  = row * GRIDW + col;
    rec.ids   = best;
    rec.lab   = glabels[(size_t)b * NBOX + n] - 1;
    rec.tx    = cx * (float)GRIDW - (float)col;
    rec.ty    = cy * (float)GRIDW - (float)row;
    rec.tw    = logf(w / ANCW[best]);
    rec.th    = logf(h / ANCH[best]);
    rec.wleft = l;   // replicate gy[...,26] usage (reference reads gboxes[...,0] here)
    sbox[n] = rec;
  }
  __syncthreads();

  float s_pos = 0.f, s_neg = 0.f, s_cls = 0.f, s_txty = 0.f, s_twth = 0.f;
  float c_pos = 0.f, c_ign = 0.f;

  int sIdx = chunk * 256 + threadIdx.x;
  if (sIdx < SLOTS) {
    int j = sIdx / HW;          // anchor, 0..4
    int k = sIdx - j * HW;      // grid cell, 0..1443  (k fastest -> coalesced)

    // Replicate scatter semantics: all -1 marks first, then tvec in box order
    // (last box wins on (cell,anchor) duplicates).
    int posbox = -1; bool cellmatch = false;
    #pragma unroll
    for (int n = 0; n < NBOX; ++n) {
      if (sbox[n].cell == k) {
        cellmatch = true;
        if (sbox[n].ids == j) posbox = n;
      }
    }

    const float* pb = pyolos + (size_t)b * CIN * HW + k;  // chan i, anchor j -> pb[(i*5+j)*HW]
    float pconf = 1.0f / (1.0f + expf(-pb[(size_t)j * HW]));
    pconf = fminf(fmaxf(pconf, EPSC), 1.0f - EPSC);

    if (posbox >= 0) {
      c_pos = 1.f;
      float om = 1.0f - pconf;
      s_pos = -0.5f * om * om * logf(pconf);     // gconf=1, mpf=1
      BoxRec rec = sbox[posbox];
      // class BCE over 20 classes, target one-hot(lab)
      float csum = 0.f;
      for (int c = 0; c < NCLS; ++c) {
        float pc = 1.0f / (1.0f + expf(-pb[(size_t)((1 + c) * NANC + j) * HW]));
        pc = fminf(fmaxf(pc, EPSC), 1.0f - EPSC);
        csum += (c == rec.lab) ? -logf(pc) : -logf(1.0f - pc);
      }
      s_cls = csum;
      // txty BCE * wleft
      float px = 1.0f / (1.0f + expf(-pb[(size_t)(21 * NANC + j) * HW]));
      float py = 1.0f / (1.0f + expf(-pb[(size_t)(22 * NANC + j) * HW]));
      px = fminf(fmaxf(px, EPSC), 1.0f - EPSC);
      py = fminf(fmaxf(py, EPSC), 1.0f - EPSC);
      float bx = -(rec.tx * logf(px) + (1.0f - rec.tx) * logf(1.0f - px));
      float by = -(rec.ty * logf(py) + (1.0f - rec.ty) * logf(1.0f - py));
      s_txty = (bx + by) * rec.wleft;
      // twth L2 * wleft
      float pw = pb[(size_t)(23 * NANC + j) * HW];
      float ph = pb[(size_t)(24 * NANC + j) * HW];
      float dw = pw - rec.tw, dh = ph - rec.th;
      s_twth = (dw * dw + dh * dh) * rec.wleft;
    } else if (cellmatch) {
      c_ign = 1.f;   // gconf = -1: contributes to neither pos nor neg
    } else {
      s_neg = -0.5f * pconf * pconf * logf(1.0f - pconf);
    }
  }

  // block reduction: wave shfl (width 64) then cross-wave via LDS
  __shared__ float red[4][7];
  int lane = threadIdx.x & 63;
  int wid  = threadIdx.x >> 6;
  for (int off = 32; off; off >>= 1) {
    s_pos  += __shfl_down(s_pos,  off, 64);
    s_neg  += __shfl_down(s_neg,  off, 64);
    s_cls  += __shfl_down(s_cls,  off, 64);
    s_txty += __shfl_down(s_txty, off, 64);
    s_twth += __shfl_down(s_twth, off, 64);
    c_pos  += __shfl_down(c_pos,  off, 64);
    c_ign  += __shfl_down(c_ign,  off, 64);
  }
  if (lane == 0) {
    red[wid][0] = s_pos;  red[wid][1] = s_neg; red[wid][2] = s_cls;
    red[wid][3] = s_txty; red[wid][4] = s_twth;
    red[wid][5] = c_pos;  red[wid][6] = c_ign;
  }
  __syncthreads();

  if (threadIdx.x == 0) {
    float a0[7] = {0, 0, 0, 0, 0, 0, 0};
    for (int w2 = 0; w2 < 4; ++w2)
      for (int q = 0; q < 7; ++q) a0[q] += red[w2][q];
    float* mine = partials + (size_t)blockIdx.x * PSTRIDE;
    for (int q = 0; q < 7; ++q) mine[q] = a0[q];
    __threadfence();
    __hip_atomic_store(&flags[blockIdx.x], MAGIC, __ATOMIC_RELEASE,
                       __HIP_MEMORY_SCOPE_AGENT);
  }

  // ---------------- finalize: block 0 only ----------------
  if (blockIdx.x != 0) return;

  // parallel spin: thread t polls flags[t], flags[t+256], ...
  {
    bool done = false;
    while (!done) {
      done = true;
      for (int i = threadIdx.x; i < NBLK; i += 256) {
        if (__hip_atomic_load(&flags[i], __ATOMIC_RELAXED,
                              __HIP_MEMORY_SCOPE_AGENT) != MAGIC) {
          done = false;
        }
      }
      if (!done) __builtin_amdgcn_s_sleep(8);
    }
  }
  __threadfence();   // device-scope fence: order flag reads before partial reads
  __syncthreads();

  // Phase A: 5 loss-term sums over all NBLK rows (independent loads, pipelined)
  double a[5] = {0, 0, 0, 0, 0};
  for (int i = threadIdx.x; i < NBLK; i += 256) {
    const float* p = partials + (size_t)i * PSTRIDE;
    #pragma unroll
    for (int q = 0; q < 5; ++q)
      a[q] += (double)__hip_atomic_load(&p[q], __ATOMIC_RELAXED,
                                        __HIP_MEMORY_SCOPE_AGENT);
  }
  __shared__ double redd[4][5];
  int lane2 = threadIdx.x & 63;
  int wid2  = threadIdx.x >> 6;
  for (int off = 32; off; off >>= 1)
    #pragma unroll
    for (int q = 0; q < 5; ++q) a[q] += __shfl_down(a[q], off, 64);
  if (lane2 == 0)
    #pragma unroll
    for (int q = 0; q < 5; ++q) redd[wid2][q] = a[q];

  // Phase B: per-batch counts — thread bb sums its batch's 29 rows (cols 5,6)
  double inv_pos = 0, inv_neg = 0, npos = 0;
  if (threadIdx.x < BATCH) {
    float cp = 0.f, cg = 0.f;
    const float* pp = partials + (size_t)threadIdx.x * BPB * PSTRIDE;
    for (int i = 0; i < BPB; ++i) {
      cp += __hip_atomic_load(&pp[i * PSTRIDE + 5], __ATOMIC_RELAXED,
                              __HIP_MEMORY_SCOPE_AGENT);
      cg += __hip_atomic_load(&pp[i * PSTRIDE + 6], __ATOMIC_RELAXED,
                              __HIP_MEMORY_SCOPE_AGENT);
    }
    double posf = (double)cp;
    double negf = (double)SLOTS - (double)cp - (double)cg;
    inv_pos = 1.0 / fmax(posf, (double)EPSC);
    inv_neg = 1.0 / fmax(negf, (double)EPSC);
    npos = posf;
  }
  for (int off = 32; off; off >>= 1) {
    inv_pos += __shfl_down(inv_pos, off, 64);
    inv_neg += __shfl_down(inv_neg, off, 64);
    npos    += __shfl_down(npos,    off, 64);
  }
  __syncthreads();

  if (threadIdx.x == 0) {
    double s[5] = {0, 0, 0, 0, 0};
    for (int w2 = 0; w2 < 4; ++w2)
      #pragma unroll
      for (int q = 0; q < 5; ++q) s[q] += redd[w2][q];
    double n_pos_tot = fmax(npos, 1.0);
    double loss = s[0] * (inv_pos / (double)BATCH)          // l_conf_pos
                + 3.0 * s[1] * (inv_neg / (double)BATCH)    // l_conf_neg
                + s[2] / n_pos_tot                          // l_cls
                + s[3] / n_pos_tot                          // l_txty
                + s[4] / n_pos_tot;                         // l_twth
    out[0] = (float)loss;
  }
}

extern "C" void kernel_launch(void* const* d_in, const int* in_sizes, int n_in,
                              void* d_out, int out_size, void* d_ws, size_t ws_size,
                              hipStream_t stream) {
  const float* pyolos  = (const float*)d_in[0];
  const float* gboxes  = (const float*)d_in[1];
  const int*   glabels = (const int*)d_in[2];
  float* out = (float*)d_out;

  // ws layout:
  //   [0,     59392)  float partials[1856][8]
  //   [59392, 66816)  unsigned flags[1856]  (0xAA poison != MAGIC; no memset)
  float*        partials = (float*)d_ws;
  unsigned int* flags    = (unsigned int*)((char*)d_ws + 59392);

  fused_kernel<<<NBLK, 256, 0, stream>>>(pyolos, gboxes, glabels,
                                         partials, flags, out);
}

// Round 7
// 96.587 us; speedup vs baseline: 1.5145x; 1.5145x over previous
//
#include <hip/hip_runtime.h>

#define BATCH 64
#define GRIDW 38
#define HW 1444            // 38*38
#define NBOX 16
#define NANC 5
#define NCLS 20
#define SLOTS 7220         // HW * NANC
#define CIN 125            // (21+4)*5
#define EPSC 0.0009765625f // 2^-10
#define BPB 29             // blocks per batch = ceil(7220/256)
#define NBLK (BATCH * BPB) // 1856
#define PSTRIDE 7          // per-block partials: 5 loss terms + pos_cnt + ign_cnt

struct BoxRec {
  int   cell;   // row*38+col
  int   ids;    // best anchor
  int   lab;    // glabel-1 in [0,20)
  float tx, ty, tw, th;
  float wleft;  // gboxes_ltrb[...,0] — the reference's "w_pos" (index 26 bug)
};

__constant__ float ANCW[5] = {0.05f, 0.12f, 0.25f, 0.45f, 0.75f};
__constant__ float ANCH[5] = {0.07f, 0.15f, 0.30f, 0.55f, 0.80f};

// Two-kernel structure (R2, measured 96.9 us). Single-launch variants with
// in-kernel grid sync all regressed (R3 137 / R4 128 / R6 146 us): per-block
// agent-scope release stores trigger per-XCD L2 writebacks (~1856 flush events
// ~= 70 us), while a kernel boundary flushes once. Keep the boundary.
__global__ void __launch_bounds__(256) main_kernel(
    const float* __restrict__ pyolos,
    const float* __restrict__ gboxes,
    const int* __restrict__ glabels,
    float* __restrict__ partials) {   // [NBLK][7]
  int b     = blockIdx.x / BPB;
  int chunk = blockIdx.x - b * BPB;

  __shared__ BoxRec sbox[NBOX];
  if (threadIdx.x < NBOX) {
    int n = threadIdx.x;
    const float* gb = gboxes + ((size_t)b * NBOX + n) * 4;
    float l  = gb[0], t = gb[1], r = gb[2], bt = gb[3];
    float cx = (l + r) * 0.5f, cy = (t + bt) * 0.5f;
    float w  = r - l,          h  = bt - t;
    int best = 0; float bestv = -1.0f;
    #pragma unroll
    for (int a = 0; a < NANC; ++a) {
      float inter = fminf(w, ANCW[a]) * fminf(h, ANCH[a]);
      float uni   = w * h + ANCW[a] * ANCH[a] - inter;
      float iou   = inter / uni;
      if (iou > bestv) { bestv = iou; best = a; }  // strict >: first-max (jnp.argmax)
    }
    int col = (int)floorf(cx * (float)GRIDW);
    int row = (int)floorf(cy * (float)GRIDW);
    col = min(max(col, 0), GRIDW - 1);
    row = min(max(row, 0), GRIDW - 1);
    BoxRec rec;
    rec.cell  = row * GRIDW + col;
    rec.ids   = best;
    rec.lab   = glabels[(size_t)b * NBOX + n] - 1;
    rec.tx    = cx * (float)GRIDW - (float)col;
    rec.ty    = cy * (float)GRIDW - (float)row;
    rec.tw    = logf(w / ANCW[best]);
    rec.th    = logf(h / ANCH[best]);
    rec.wleft = l;   // replicate gy[...,26] usage (reference reads gboxes[...,0] here)
    sbox[n] = rec;
  }
  __syncthreads();

  float s_pos = 0.f, s_neg = 0.f, s_cls = 0.f, s_txty = 0.f, s_twth = 0.f;
  float c_pos = 0.f, c_ign = 0.f;

  int sIdx = chunk * 256 + threadIdx.x;
  if (sIdx < SLOTS) {
    int j = sIdx / HW;          // anchor, 0..4
    int k = sIdx - j * HW;      // grid cell, 0..1443  (k fastest -> coalesced)

    // Replicate scatter semantics: all -1 marks first, then tvec in box order
    // (last box wins on (cell,anchor) duplicates).
    int posbox = -1; bool cellmatch = false;
    #pragma unroll
    for (int n = 0; n < NBOX; ++n) {
      if (sbox[n].cell == k) {
        cellmatch = true;
        if (sbox[n].ids == j) posbox = n;
      }
    }

    const float* pb = pyolos + (size_t)b * CIN * HW + k;  // chan i, anchor j -> pb[(i*5+j)*HW]
    float pconf = 1.0f / (1.0f + expf(-pb[(size_t)j * HW]));
    pconf = fminf(fmaxf(pconf, EPSC), 1.0f - EPSC);

    if (posbox >= 0) {
      c_pos = 1.f;
      float om = 1.0f - pconf;
      s_pos = -0.5f * om * om * logf(pconf);     // gconf=1, mpf=1
      BoxRec rec = sbox[posbox];
      // class BCE over 20 classes, target one-hot(lab)
      float csum = 0.f;
      for (int c = 0; c < NCLS; ++c) {
        float pc = 1.0f / (1.0f + expf(-pb[(size_t)((1 + c) * NANC + j) * HW]));
        pc = fminf(fmaxf(pc, EPSC), 1.0f - EPSC);
        csum += (c == rec.lab) ? -logf(pc) : -logf(1.0f - pc);
      }
      s_cls = csum;
      // txty BCE * wleft
      float px = 1.0f / (1.0f + expf(-pb[(size_t)(21 * NANC + j) * HW]));
      float py = 1.0f / (1.0f + expf(-pb[(size_t)(22 * NANC + j) * HW]));
      px = fminf(fmaxf(px, EPSC), 1.0f - EPSC);
      py = fminf(fmaxf(py, EPSC), 1.0f - EPSC);
      float bx = -(rec.tx * logf(px) + (1.0f - rec.tx) * logf(1.0f - px));
      float by = -(rec.ty * logf(py) + (1.0f - rec.ty) * logf(1.0f - py));
      s_txty = (bx + by) * rec.wleft;
      // twth L2 * wleft
      float pw = pb[(size_t)(23 * NANC + j) * HW];
      float ph = pb[(size_t)(24 * NANC + j) * HW];
      float dw = pw - rec.tw, dh = ph - rec.th;
      s_twth = (dw * dw + dh * dh) * rec.wleft;
    } else if (cellmatch) {
      c_ign = 1.f;   // gconf = -1: contributes to neither pos nor neg
    } else {
      s_neg = -0.5f * pconf * pconf * logf(1.0f - pconf);
    }
  }

  // block reduction: wave shfl (width 64) then cross-wave via LDS
  __shared__ float red[4][PSTRIDE];
  int lane = threadIdx.x & 63;
  int wid  = threadIdx.x >> 6;
  for (int off = 32; off; off >>= 1) {
    s_pos  += __shfl_down(s_pos,  off, 64);
    s_neg  += __shfl_down(s_neg,  off, 64);
    s_cls  += __shfl_down(s_cls,  off, 64);
    s_txty += __shfl_down(s_txty, off, 64);
    s_twth += __shfl_down(s_twth, off, 64);
    c_pos  += __shfl_down(c_pos,  off, 64);
    c_ign  += __shfl_down(c_ign,  off, 64);
  }
  if (lane == 0) {
    red[wid][0] = s_pos;  red[wid][1] = s_neg; red[wid][2] = s_cls;
    red[wid][3] = s_txty; red[wid][4] = s_twth;
    red[wid][5] = c_pos;  red[wid][6] = c_ign;
  }
  __syncthreads();
  if (threadIdx.x == 0) {
    float a[PSTRIDE] = {0, 0, 0, 0, 0, 0, 0};
    for (int w2 = 0; w2 < 4; ++w2)
      for (int q = 0; q < PSTRIDE; ++q) a[q] += red[w2][q];
    float* mine = partials + (size_t)blockIdx.x * PSTRIDE;
    for (int q = 0; q < PSTRIDE; ++q) mine[q] = a[q];
  }
}

// ---------------- Kernel 2: final deterministic reduction ----------------
__global__ void finalize_kernel(const float* __restrict__ partials,
                                float* __restrict__ out) {
  // 5 loss-term sums over all NBLK blocks (all 256 threads)
  double a[5] = {0, 0, 0, 0, 0};
  for (int i = threadIdx.x; i < NBLK; i += 256) {
    const float* p = partials + (size_t)i * PSTRIDE;
    a[0] += p[0]; a[1] += p[1]; a[2] += p[2]; a[3] += p[3]; a[4] += p[4];
  }
  __shared__ double redd[4][5];
  int lane = threadIdx.x & 63;
  int wid  = threadIdx.x >> 6;
  for (int off = 32; off; off >>= 1)
    for (int q = 0; q < 5; ++q) a[q] += __shfl_down(a[q], off, 64);
  if (lane == 0)
    for (int q = 0; q < 5; ++q) redd[wid][q] = a[q];

  // per-batch count terms: thread b sums its batch's 29 blocks (threads 0..63 = wave 0)
  double inv_pos = 0, inv_neg = 0, npos = 0;
  if (threadIdx.x < BATCH) {
    float p = 0.f, g = 0.f;
    const float* pp = partials + (size_t)threadIdx.x * BPB * PSTRIDE;
    for (int i = 0; i < BPB; ++i) { p += pp[i * PSTRIDE + 5]; g += pp[i * PSTRIDE + 6]; }
    double posf = (double)p;
    double negf = (double)SLOTS - (double)p - (double)g;
    inv_pos = 1.0 / fmax(posf, (double)EPSC);
    inv_neg = 1.0 / fmax(negf, (double)EPSC);
    npos = posf;
  }
  for (int off = 32; off; off >>= 1) {
    inv_pos += __shfl_down(inv_pos, off, 64);
    inv_neg += __shfl_down(inv_neg, off, 64);
    npos    += __shfl_down(npos,    off, 64);
  }
  __syncthreads();
  if (threadIdx.x == 0) {
    double s[5] = {0, 0, 0, 0, 0};
    for (int w2 = 0; w2 < 4; ++w2)
      for (int q = 0; q < 5; ++q) s[q] += redd[w2][q];
    double n_pos_tot = fmax(npos, 1.0);
    double loss = s[0] * (inv_pos / (double)BATCH)          // l_conf_pos
                + 3.0 * s[1] * (inv_neg / (double)BATCH)    // l_conf_neg
                + s[2] / n_pos_tot                          // l_cls
                + s[3] / n_pos_tot                          // l_txty
                + s[4] / n_pos_tot;                         // l_twth
    out[0] = (float)loss;
  }
}

extern "C" void kernel_launch(void* const* d_in, const int* in_sizes, int n_in,
                              void* d_out, int out_size, void* d_ws, size_t ws_size,
                              hipStream_t stream) {
  const float* pyolos  = (const float*)d_in[0];
  const float* gboxes  = (const float*)d_in[1];
  const int*   glabels = (const int*)d_in[2];
  float* out = (float*)d_out;

  // ws layout: float partials[1856][7]  (52 KB) — fully written by main_kernel
  // before finalize reads it, so 0xAA poison is harmless. No memset needed.
  float* partials = (float*)d_ws;

  main_kernel<<<NBLK, 256, 0, stream>>>(pyolos, gboxes, glabels, partials);
  finalize_kernel<<<1, 256, 0, stream>>>(partials, out);
}